// Round 4
// baseline (2409.243 us; speedup 1.0000x reference)
//
#include <hip/hip_runtime.h>
#include <hip/hip_bf16.h>

// GRU scan with sparse resets. T=1024, B=256, D=128, H=128.
// Round 4: producer/consumer wave specialization. 16 blocks (16 batch each),
// 512 threads = 8 waves: waves 0-3 = h-waves (recurrent critical path),
// waves 4-7 = x-waves (compute gi[t+1] = x@Wi one step ahead, off-path).
// gi crosses waves through LDS in identity C-layout (f16, b64, no transpose).
// x is loaded global->registers (2-step pipeline, static regs), never LDS.
// h tile in LDS f16 with XOR swizzle; h-wave MFMA cluster setprio(1).

#define T_STEPS 1024
#define B_SZ 256
#define D_SZ 128
#define H_SZ 128
#define BPB 16
#define NTHR 512

typedef _Float16 f16x8 __attribute__((ext_vector_type(8)));
typedef _Float16 f16x4 __attribute__((ext_vector_type(4)));
typedef float f32x4 __attribute__((ext_vector_type(4)));

__device__ __forceinline__ float fastrcp(float x) {
#if __has_builtin(__builtin_amdgcn_rcpf)
  return __builtin_amdgcn_rcpf(x);
#else
  return 1.0f / x;
#endif
}

// swizzled byte offset of element (row, colf16) in a [16][128] f16 tile
__device__ __forceinline__ int swz_off(int row, int colf16) {
  return row * 256 + ((colf16 * 2) ^ ((row & 7) << 4));
}

// issue 8 float4 loads of x[TT] row s, k-slice q*8.. into Y (fire & forget)
#define ISSUE_X(TT, Y) { \
    int tl_ = (TT); if (tl_ > T_STEPS - 1) tl_ = T_STEPS - 1; \
    const float* xb_ = &seq[((size_t)tl_ * B_SZ + bb + s) * D_SZ + q * 8]; \
    Y[0] = *(const float4*)(xb_ + 0);   Y[1] = *(const float4*)(xb_ + 4); \
    Y[2] = *(const float4*)(xb_ + 32);  Y[3] = *(const float4*)(xb_ + 36); \
    Y[4] = *(const float4*)(xb_ + 64);  Y[5] = *(const float4*)(xb_ + 68); \
    Y[6] = *(const float4*)(xb_ + 96);  Y[7] = *(const float4*)(xb_ + 100); }

// compute gi[TT+1] from Y (= x[TT+1] f32) and store f16 C-layout to gib
#define XGI(TT, Y) { \
    f16x8 xf_[4]; \
    _Pragma("unroll") for (int kk = 0; kk < 4; kk++) { \
      f16x8 f_; \
      f_[0] = (_Float16)Y[2*kk].x;   f_[1] = (_Float16)Y[2*kk].y; \
      f_[2] = (_Float16)Y[2*kk].z;   f_[3] = (_Float16)Y[2*kk].w; \
      f_[4] = (_Float16)Y[2*kk+1].x; f_[5] = (_Float16)Y[2*kk+1].y; \
      f_[6] = (_Float16)Y[2*kk+1].z; f_[7] = (_Float16)Y[2*kk+1].w; \
      xf_[kk] = f_; } \
    f32x4 ac_[3][2]; \
    _Pragma("unroll") for (int g3_ = 0; g3_ < 3; g3_++) \
      _Pragma("unroll") for (int cg_ = 0; cg_ < 2; cg_++) \
        ac_[g3_][cg_] = (f32x4){0.f, 0.f, 0.f, 0.f}; \
    _Pragma("unroll") for (int kk = 0; kk < 4; kk++) \
      _Pragma("unroll") for (int g3_ = 0; g3_ < 3; g3_++) \
        _Pragma("unroll") for (int cg_ = 0; cg_ < 2; cg_++) \
          ac_[g3_][cg_] = __builtin_amdgcn_mfma_f32_16x16x32_f16( \
              xf_[kk], wF[g3_][cg_][kk], ac_[g3_][cg_], 0, 0, 0); \
    _Float16* gw_ = gib[((TT) + 1) & 1]; \
    _Pragma("unroll") for (int g3_ = 0; g3_ < 3; g3_++) \
      _Pragma("unroll") for (int cg_ = 0; cg_ < 2; cg_++) { \
        const int tile_ = g3_ * 8 + hw * 2 + cg_; \
        f16x4 p_; \
        _Pragma("unroll") for (int j = 0; j < 4; j++) \
          p_[j] = (_Float16)ac_[g3_][cg_][j]; \
        *(f16x4*)&gw_[(tile_ * 64 + lane) * 4] = p_; } }

#define XSTEP(TT, YCUR) { \
    if ((TT) < T_STEPS - 1) { XGI(TT, YCUR) } \
    ISSUE_X((TT) + 3, YCUR) }

#define HSTEP(TT) { \
    const int p_ = (TT) & 1; \
    const _Float16* gr_ = gib[p_]; \
    f32x4 acc_[3][2]; f32x4 gN_[2]; \
    _Pragma("unroll") for (int g3_ = 0; g3_ < 2; g3_++) \
      _Pragma("unroll") for (int cg_ = 0; cg_ < 2; cg_++) { \
        const int tile_ = g3_ * 8 + hw * 2 + cg_; \
        f16x4 v_ = *(const f16x4*)&gr_[(tile_ * 64 + lane) * 4]; \
        f32x4 a_; \
        _Pragma("unroll") for (int j = 0; j < 4; j++) a_[j] = (float)v_[j]; \
        acc_[g3_][cg_] = a_; } \
    _Pragma("unroll") for (int cg_ = 0; cg_ < 2; cg_++) { \
        const int tile_ = 16 + hw * 2 + cg_; \
        f16x4 v_ = *(const f16x4*)&gr_[(tile_ * 64 + lane) * 4]; \
        f32x4 a_; \
        _Pragma("unroll") for (int j = 0; j < 4; j++) a_[j] = (float)v_[j]; \
        gN_[cg_] = a_; \
        acc_[2][cg_] = (f32x4){0.f, 0.f, 0.f, 0.f}; } \
    f16x8 hf_[4]; \
    _Pragma("unroll") for (int kk = 0; kk < 4; kk++) \
      hf_[kk] = *(const f16x8*)((const char*)ht[p_] + swz_off(s, kk * 32 + q * 8)); \
    __builtin_amdgcn_s_setprio(1); \
    _Pragma("unroll") for (int kk = 0; kk < 4; kk++) \
      _Pragma("unroll") for (int g3_ = 0; g3_ < 3; g3_++) \
        _Pragma("unroll") for (int cg_ = 0; cg_ < 2; cg_++) \
          acc_[g3_][cg_] = __builtin_amdgcn_mfma_f32_16x16x32_f16( \
              hf_[kk], wF[g3_][cg_][kk], acc_[g3_][cg_], 0, 0, 0); \
    __builtin_amdgcn_s_setprio(0); \
    const unsigned rn_ = rstm[((TT) + 1) & (T_STEPS - 1)]; \
    _Float16* hwp_ = ht[p_ ^ 1]; \
    _Pragma("unroll") for (int cg_ = 0; cg_ < 2; cg_++) { \
      const int c_ = hw * 32 + cg_ * 16 + s; \
      _Pragma("unroll") for (int j = 0; j < 4; j++) { \
        const int row_ = q * 4 + j; \
        const float ar_ = acc_[0][cg_][j] + bhv[0][cg_]; \
        const float az_ = acc_[1][cg_][j] + bhv[1][cg_]; \
        const float an_ = acc_[2][cg_][j] + bhv[2][cg_]; \
        const float r_ = fastrcp(1.f + __expf(-ar_)); \
        const float z_ = fastrcp(1.f + __expf(-az_)); \
        float ta_ = gN_[cg_][j] + r_ * an_; \
        ta_ = fminf(fmaxf(ta_, -15.f), 15.f); \
        const float e2_ = __expf(2.f * ta_); \
        const float n_ = (e2_ - 1.f) * fastrcp(e2_ + 1.f); \
        const float hnew_ = n_ + z_ * (hu[cg_][j] - n_); \
        ys[((size_t)(TT) * B_SZ + bb + row_) * H_SZ + c_] = hnew_; \
        if ((TT) == T_STEPS - 1) out[(size_t)(bb + row_) * H_SZ + c_] = hnew_; \
        const float he_ = ((rn_ >> row_) & 1u) ? h0r[cg_][j] : hnew_; \
        hu[cg_][j] = he_; \
        *(_Float16*)((char*)hwp_ + swz_off(row_, c_)) = (_Float16)he_; } } }

__global__ __launch_bounds__(NTHR, 2)
void gru_pc_kernel(const float* __restrict__ seq,
                   const int* __restrict__ resets,
                   const float* __restrict__ h0,
                   const float* __restrict__ Wi,
                   const float* __restrict__ Wh,
                   const float* __restrict__ bh,
                   float* __restrict__ out) {
  const int bb = blockIdx.x * BPB;
  const int tid = threadIdx.x;
  const int w = tid >> 6;
  const int lane = tid & 63;
  const int q = lane >> 4;        // A k-group / C row group
  const int s = lane & 15;        // A row (batch) / B,C col
  const bool is_h = (w < 4);
  const int hw = w & 3;

  __shared__ unsigned rstm[T_STEPS];                       // 4 KB
  __shared__ __align__(16) _Float16 ht[2][BPB * H_SZ];     // 8 KB, swizzled
  __shared__ __align__(16) _Float16 gib[2][24 * 64 * 4];   // 24 KB, C-layout

  for (int tt = tid; tt < T_STEPS; tt += NTHR) {
    const int* rp = &resets[(size_t)tt * B_SZ + bb];
    unsigned m = 0;
#pragma unroll
    for (int j = 0; j < BPB; j++) m |= (rp[j] != 0 ? 1u : 0u) << j;
    rstm[tt] = m;
  }

  // --- weights -> registers (B-frag: col = s, k = q*8 + j within chunk) ---
  // h-waves hold Wh, x-waves hold Wi. Gate g3, colgroup cg -> W column
  // g3*128 + hw*32 + cg*16 + s. gi/gh n-tile index = g3*8 + hw*2 + cg.
  const float* Wsel = is_h ? Wh : Wi;
  f16x8 wF[3][2][4];
#pragma unroll
  for (int g3 = 0; g3 < 3; g3++)
#pragma unroll
    for (int cg = 0; cg < 2; cg++) {
      const int col = g3 * H_SZ + hw * 32 + cg * 16 + s;
#pragma unroll
      for (int kk = 0; kk < 4; kk++) {
        f16x8 f;
#pragma unroll
        for (int j = 0; j < 8; j++)
          f[j] = (_Float16)Wsel[(size_t)(kk * 32 + q * 8 + j) * 384 + col];
        wF[g3][cg][kk] = f;
      }
    }

  float h0r[2][4], hu[2][4], bhv[3][2];
  float4 ya[8], yb[8];

  if (is_h) {
#pragma unroll
    for (int cg = 0; cg < 2; cg++) {
      const int c = hw * 32 + cg * 16 + s;
      bhv[0][cg] = bh[c];
      bhv[1][cg] = bh[H_SZ + c];
      bhv[2][cg] = bh[2 * H_SZ + c];
#pragma unroll
      for (int j = 0; j < 4; j++) {
        const int row = q * 4 + j;
        const float v = h0[(size_t)(bb + row) * H_SZ + c];
        h0r[cg][j] = v;
        hu[cg][j] = v;   // reset at t=0 maps h0 -> h0: no-op
        *(_Float16*)((char*)ht[0] + swz_off(row, c)) = (_Float16)v;
      }
    }
  } else {
    ISSUE_X(0, ya)
    XGI(-1, ya)          // gi[0] -> gib[0]
    ISSUE_X(1, ya)       // x[1] in flight, consumed at t=0
    ISSUE_X(2, yb)       // x[2] in flight, consumed at t=1
  }
  __syncthreads();

  float* ys = out + (size_t)B_SZ * H_SZ;   // out = [final_carry] ++ [ys]

#pragma unroll 1
  for (int t = 0; t < T_STEPS; t += 2) {
    if (is_h) { HSTEP(t) } else { XSTEP(t, ya) }
    __syncthreads();
    if (is_h) { HSTEP(t + 1) } else { XSTEP(t + 1, yb) }
    __syncthreads();
  }
}

extern "C" void kernel_launch(void* const* d_in, const int* in_sizes, int n_in,
                              void* d_out, int out_size, void* d_ws, size_t ws_size,
                              hipStream_t stream) {
  const float* seq    = (const float*)d_in[0];
  const int*   resets = (const int*)d_in[1];
  const float* h0     = (const float*)d_in[2];
  const float* Wi     = (const float*)d_in[3];
  const float* Wh     = (const float*)d_in[4];
  const float* bh     = (const float*)d_in[5];
  (void)in_sizes; (void)n_in; (void)d_ws; (void)ws_size; (void)out_size;

  gru_pc_kernel<<<B_SZ / BPB, NTHR, 0, stream>>>(seq, resets, h0, Wi, Wh, bh,
                                                 (float*)d_out);
}

// Round 5
// 734.135 us; speedup vs baseline: 3.2817x; 3.2817x over previous
//
#include <hip/hip_runtime.h>
#include <hip/hip_bf16.h>

// GRU scan with sparse resets. T=1024, B=256, D=128, H=128.
// Round 5: two-phase. Phase 1 (throughput): gi = seq @ Wi as f16 into d_ws
// via MFMA (26 GFLOP, HBM-bound). Phase 2 (latency): round-2 scan structure
// minus the x-projection: 48 dot2/lane (h@Wh only), gi streamed from ws with
// 4-step register prefetch, 8-shfl butterfly reduce, clamp-free tanh.
// Fallback to the round-2 fused kernel if ws_size < 201 MB.

#define T_STEPS 1024
#define B_SZ 256
#define D_SZ 128
#define H_SZ 128
#define NTHR 512

typedef _Float16 h2 __attribute__((ext_vector_type(2)));
typedef _Float16 h8 __attribute__((ext_vector_type(8)));
typedef _Float16 f16x8 __attribute__((ext_vector_type(8)));
typedef float f32x4 __attribute__((ext_vector_type(4)));

union U8 { h8 v; h2 p[4]; };

__device__ __forceinline__ float dot2f(h2 a, h2 b, float c) {
#if __has_builtin(__builtin_amdgcn_fdot2)
  return __builtin_amdgcn_fdot2(a, b, c, false);
#else
  return c + (float)a.x * (float)b.x + (float)a.y * (float)b.y;
#endif
}

__device__ __forceinline__ float fastrcp(float x) {
#if __has_builtin(__builtin_amdgcn_rcpf)
  return __builtin_amdgcn_rcpf(x);
#else
  return 1.0f / x;
#endif
}

// ---------------- phase 1: gi[t*B+b][384] (f16) = seq @ Wi ----------------
__global__ __launch_bounds__(256, 2)
void gi_gemm(const float* __restrict__ seq, const float* __restrict__ Wi,
             _Float16* __restrict__ gi) {
  const int tid = threadIdx.x;
  const int w = tid >> 6, lane = tid & 63;
  const int q = lane >> 4, s = lane & 15;

  // B-frags: wave w owns cols [w*96, w*96+96) as 6 n-tiles.
  f16x8 wF[6][4];
#pragma unroll
  for (int j = 0; j < 6; j++) {
    const int col = w * 96 + j * 16 + s;
#pragma unroll
    for (int kk = 0; kk < 4; kk++) {
      f16x8 f;
#pragma unroll
      for (int e = 0; e < 8; e++)
        f[e] = (_Float16)Wi[(size_t)(kk * 32 + q * 8 + e) * 384 + col];
      wF[j][kk] = f;
    }
  }

  __shared__ __align__(16) _Float16 gis[16 * 384];
  const int NROWTILES = (T_STEPS * B_SZ) / 16;

  for (int r = blockIdx.x; r < NROWTILES; r += gridDim.x) {
    const float* xr = &seq[((size_t)r * 16 + s) * D_SZ];
    f16x8 af[4];
#pragma unroll
    for (int kk = 0; kk < 4; kk++) {
      float4 u0 = *(const float4*)(xr + kk * 32 + q * 8);
      float4 u1 = *(const float4*)(xr + kk * 32 + q * 8 + 4);
      f16x8 f;
      f[0] = (_Float16)u0.x; f[1] = (_Float16)u0.y;
      f[2] = (_Float16)u0.z; f[3] = (_Float16)u0.w;
      f[4] = (_Float16)u1.x; f[5] = (_Float16)u1.y;
      f[6] = (_Float16)u1.z; f[7] = (_Float16)u1.w;
      af[kk] = f;
    }
    f32x4 acc[6];
#pragma unroll
    for (int j = 0; j < 6; j++) acc[j] = (f32x4){0.f, 0.f, 0.f, 0.f};
#pragma unroll
    for (int kk = 0; kk < 4; kk++)
#pragma unroll
      for (int j = 0; j < 6; j++)
        acc[j] = __builtin_amdgcn_mfma_f32_16x16x32_f16(af[kk], wF[j][kk],
                                                        acc[j], 0, 0, 0);
#pragma unroll
    for (int j = 0; j < 6; j++) {
      const int col = w * 96 + j * 16 + s;
#pragma unroll
      for (int e = 0; e < 4; e++)
        gis[(q * 4 + e) * 384 + col] = (_Float16)acc[j][e];
    }
    __syncthreads();
    const size_t base = (size_t)r * 16 * 384;
#pragma unroll
    for (int i = 0; i < 3; i++) {
      const int idx = tid + i * 256;   // 768 chunks of 8 f16 (16 B)
      *(float4*)(gi + base + (size_t)idx * 8) = *(const float4*)(gis + idx * 8);
    }
    __syncthreads();
  }
}

// ---------------- phase 2: latency-optimized scan (h-part only) -----------
#define GILOAD(T_, R_, Z_, N_) { \
    int tl_ = (T_); if (tl_ > T_STEPS - 1) tl_ = T_STEPS - 1; \
    const _Float16* gp_ = gib + (size_t)tl_ * (B_SZ * 384); \
    R_ = gp_[c]; Z_ = gp_[128 + c]; N_ = gp_[256 + c]; }

#define STEP(T_, R_, Z_, N_) { \
    const int p_ = (T_) & 1; \
    const h2* hb_ = (const h2*)&hh16[p_][g * 32]; \
    float cr_ = 0.f, cz_ = 0.f, cn_ = 0.f, ci_ = 0.f; \
    if (g0) { cr_ = (float)R_; cz_ = (float)Z_; ci_ = (float)N_; } \
    _Pragma("unroll") for (int j = 0; j < 16; j++) { \
      const h2 hv_ = hb_[j]; \
      cr_ = dot2f(hv_, whR[0][j], cr_); \
      cz_ = dot2f(hv_, whR[1][j], cz_); \
      cn_ = dot2f(hv_, whR[2][j], cn_); } \
    if (g0) { GILOAD((T_) + 4, R_, Z_, N_) } \
    cr_ += __shfl_xor(cr_, 16, 64); cz_ += __shfl_xor(cz_, 16, 64); \
    cn_ += __shfl_xor(cn_, 16, 64); ci_ += __shfl_xor(ci_, 16, 64); \
    cr_ += __shfl_xor(cr_, 32, 64); cz_ += __shfl_xor(cz_, 32, 64); \
    cn_ += __shfl_xor(cn_, 32, 64); ci_ += __shfl_xor(ci_, 32, 64); \
    const float ar_ = cr_ + bhr, az_ = cz_ + bhz, ah_ = cn_ + bhn; \
    const float r_ = fastrcp(1.f + __expf(-ar_)); \
    const float z_ = fastrcp(1.f + __expf(-az_)); \
    const float ta_ = ci_ + r_ * ah_; \
    const float e2_ = __expf(2.f * ta_); \
    const float n_ = 1.f - 2.f * fastrcp(e2_ + 1.f);  /* NaN-free tanh */ \
    const float hnew_ = n_ + z_ * (hu - n_); \
    const int rn_ = rst[((T_) + 1) & (T_STEPS - 1)]; \
    hu = rn_ ? h0c : hnew_; \
    if (g0) { \
      ys[((size_t)(T_) * B_SZ + b) * H_SZ + c] = hnew_; \
      hh16[p_ ^ 1][c] = (_Float16)hu; \
      if ((T_) == T_STEPS - 1) out[(size_t)b * H_SZ + c] = hnew_; } \
    __syncthreads(); }

__global__ __launch_bounds__(NTHR, 2)
void gru_scan2(const _Float16* __restrict__ gi,
               const int* __restrict__ resets,
               const float* __restrict__ h0,
               const float* __restrict__ Wh,
               const float* __restrict__ bh,
               float* __restrict__ out) {
  const int b = blockIdx.x;
  const int tid = threadIdx.x;
  const int w = tid >> 6;
  const int lane = tid & 63;
  const int c = (w << 4) | (lane & 15);  // hidden column 0..127
  const int g = lane >> 4;               // k-group 0..3
  const bool g0 = (g == 0);

  __shared__ int rst[T_STEPS];
  __shared__ __align__(16) _Float16 hh16[2][H_SZ];

  for (int i = tid; i < T_STEPS; i += NTHR) rst[i] = resets[(size_t)i * B_SZ + b];

  h2 whR[3][16];
  const int k0 = g * 32;
#pragma unroll
  for (int ch = 0; ch < 3; ch++) {
    const int col = ch * H_SZ + c;
#pragma unroll
    for (int j = 0; j < 16; j++) {
      const int k = k0 + 2 * j;
      h2 wb; wb.x = (_Float16)Wh[(size_t)k * 384 + col];
             wb.y = (_Float16)Wh[(size_t)(k + 1) * 384 + col];
      whR[ch][j] = wb;
    }
  }

  const float bhr = bh[c], bhz = bh[H_SZ + c], bhn = bh[2 * H_SZ + c];
  const float h0c = h0[(size_t)b * H_SZ + c];
  float hu = h0c;

  if (tid < H_SZ) hh16[0][tid] = (_Float16)h0[(size_t)b * H_SZ + tid];

  const _Float16* gib = gi + (size_t)b * 384;
  _Float16 rA, zA, nA, rB, zB, nB, rC, zC, nC, rD, zD, nD;
  if (g0) {
    GILOAD(0, rA, zA, nA)
    GILOAD(1, rB, zB, nB)
    GILOAD(2, rC, zC, nC)
    GILOAD(3, rD, zD, nD)
  }
  __syncthreads();

  float* ys = out + (size_t)B_SZ * H_SZ;  // out = [final_carry] ++ [ys]

#pragma unroll 1
  for (int t = 0; t < T_STEPS; t += 4) {
    STEP(t,     rA, zA, nA)
    STEP(t + 1, rB, zB, nB)
    STEP(t + 2, rC, zC, nC)
    STEP(t + 3, rD, zD, nD)
  }
}

// ---------------- fallback: round-2 fused kernel (ws too small) -----------
__global__ __launch_bounds__(NTHR, 2)
void gru_scan_fb(const float* __restrict__ seq,
                 const int* __restrict__ resets,
                 const float* __restrict__ h0,
                 const float* __restrict__ Wi,
                 const float* __restrict__ Wh,
                 const float* __restrict__ bh,
                 float* __restrict__ out) {
  const int b = blockIdx.x;
  const int tid = threadIdx.x;
  const int w = tid >> 6;
  const int lane = tid & 63;
  const int c = (w << 4) | (lane & 15);
  const int g = lane >> 4;

  __shared__ int rst[T_STEPS];
  __shared__ __align__(16) _Float16 x16[2][D_SZ];
  __shared__ __align__(16) _Float16 hh16[2][H_SZ];

  for (int i = tid; i < T_STEPS; i += NTHR) rst[i] = resets[(size_t)i * B_SZ + b];

  h2 wiR[3][16], whR[3][16];
  const int k0 = g * 32;
#pragma unroll
  for (int ch = 0; ch < 3; ch++) {
    const int col = ch * H_SZ + c;
#pragma unroll
    for (int j = 0; j < 16; j++) {
      const int k = k0 + 2 * j;
      h2 wa; wa.x = (_Float16)Wi[(size_t)k * 384 + col];
             wa.y = (_Float16)Wi[(size_t)(k + 1) * 384 + col];
      wiR[ch][j] = wa;
      h2 wb; wb.x = (_Float16)Wh[(size_t)k * 384 + col];
             wb.y = (_Float16)Wh[(size_t)(k + 1) * 384 + col];
      whR[ch][j] = wb;
    }
  }

  const float bhr = bh[c], bhz = bh[H_SZ + c], bhn = bh[2 * H_SZ + c];
  const float h0c = h0[(size_t)b * H_SZ + c];
  float hu = h0c;

  if (tid < H_SZ) {
    hh16[0][tid] = (_Float16)h0[(size_t)b * H_SZ + tid];
    x16[0][tid]  = (_Float16)seq[((size_t)0 * B_SZ + b) * D_SZ + tid];
  }
  float xA = 0.f, xB = 0.f;
  if (tid < D_SZ) {
    xA = seq[((size_t)1 * B_SZ + b) * D_SZ + tid];
    xB = seq[((size_t)2 * B_SZ + b) * D_SZ + tid];
  }
  __syncthreads();

  float* ys = out + (size_t)B_SZ * H_SZ;

#pragma unroll 1
  for (int t = 0; t < T_STEPS; t++) {
    const int p = t & 1;
    const int rnext = rst[(t + 1) & (T_STEPS - 1)];

    const h8* xb = (const h8*)&x16[p][g * 32];
    const h8* hb = (const h8*)&hh16[p][g * 32];
    float cr = 0.f, cz = 0.f, ci = 0.f, chn = 0.f;
#pragma unroll
    for (int q = 0; q < 4; q++) {
      U8 ux, uh; ux.v = xb[q]; uh.v = hb[q];
#pragma unroll
      for (int j = 0; j < 4; j++) {
        const int idx = q * 4 + j;
        cr  = dot2f(ux.p[j], wiR[0][idx], cr);
        cz  = dot2f(ux.p[j], wiR[1][idx], cz);
        ci  = dot2f(ux.p[j], wiR[2][idx], ci);
        cr  = dot2f(uh.p[j], whR[0][idx], cr);
        cz  = dot2f(uh.p[j], whR[1][idx], cz);
        chn = dot2f(uh.p[j], whR[2][idx], chn);
      }
    }
    cr  += __shfl_xor(cr, 16, 64);
    cz  += __shfl_xor(cz, 16, 64);
    ci  += __shfl_xor(ci, 16, 64);
    chn += __shfl_xor(chn, 16, 64);
    cr  += __shfl_xor(cr, 32, 64);
    cz  += __shfl_xor(cz, 32, 64);
    ci  += __shfl_xor(ci, 32, 64);
    chn += __shfl_xor(chn, 32, 64);

    const float ar = cr + bhr;
    const float az = cz + bhz;
    const float ah = chn + bhn;
    const float r = fastrcp(1.f + __expf(-ar));
    const float z = fastrcp(1.f + __expf(-az));
    const float ta = ci + r * ah;
    const float e2 = __expf(2.f * ta);
    const float n = 1.f - 2.f * fastrcp(e2 + 1.f);
    const float hnew = n + z * (hu - n);
    const float hunew = rnext ? h0c : hnew;
    hu = hunew;

    if (g == 0) {
      ys[((size_t)t * B_SZ + b) * H_SZ + c] = hnew;
      hh16[p ^ 1][c] = (_Float16)hunew;
      if (t == T_STEPS - 1) out[(size_t)b * H_SZ + c] = hnew;
    }
    if (tid < D_SZ) {
      x16[p ^ 1][tid] = (_Float16)xA;
      xA = xB;
      int tt = t + 3; if (tt > T_STEPS - 1) tt = T_STEPS - 1;
      xB = seq[((size_t)tt * B_SZ + b) * D_SZ + tid];
    }
    __syncthreads();
  }
}

extern "C" void kernel_launch(void* const* d_in, const int* in_sizes, int n_in,
                              void* d_out, int out_size, void* d_ws, size_t ws_size,
                              hipStream_t stream) {
  const float* seq    = (const float*)d_in[0];
  const int*   resets = (const int*)d_in[1];
  const float* h0     = (const float*)d_in[2];
  const float* Wi     = (const float*)d_in[3];
  const float* Wh     = (const float*)d_in[4];
  const float* bh     = (const float*)d_in[5];
  (void)in_sizes; (void)n_in; (void)out_size;

  const size_t need = (size_t)T_STEPS * B_SZ * 384 * sizeof(_Float16);
  if (ws_size >= need && d_ws != nullptr) {
    _Float16* gi = (_Float16*)d_ws;
    gi_gemm<<<1024, 256, 0, stream>>>(seq, Wi, gi);
    gru_scan2<<<B_SZ, NTHR, 0, stream>>>(gi, resets, h0, Wh, bh, (float*)d_out);
  } else {
    gru_scan_fb<<<B_SZ, NTHR, 0, stream>>>(seq, resets, h0, Wi, Wh, bh,
                                           (float*)d_out);
  }
}

// Round 6
// 656.114 us; speedup vs baseline: 3.6720x; 1.1189x over previous
//
#include <hip/hip_runtime.h>
#include <hip/hip_bf16.h>

// GRU scan with sparse resets. T=1024, B=256, D=128, H=128.
// Round 6: two-phase. Phase 1: gi = seq @ Wi (f16, MFMA, HBM-bound, ~74us).
// Phase 2: latency scan, 256 blocks x 256 thr (4 waves = 1/SIMD).
// Wave w owns columns c = w*32 + (lane&31); g = lane>>5 is the k-half.
// One shfl_xor(32) butterfly level. Custom barrier (lgkmcnt-only: ys stores
// and gi prefetch loads stay in flight across steps). ys stores batched 8
// steps deep in static registers. gi prefetched 4 steps ahead.

#define T_STEPS 1024
#define B_SZ 256
#define D_SZ 128
#define H_SZ 128

typedef _Float16 h2 __attribute__((ext_vector_type(2)));
typedef _Float16 h8 __attribute__((ext_vector_type(8)));
typedef _Float16 f16x8 __attribute__((ext_vector_type(8)));
typedef float f32x4 __attribute__((ext_vector_type(4)));

union U8 { h8 v; h2 p[4]; };

__device__ __forceinline__ float dot2f(h2 a, h2 b, float c) {
#if __has_builtin(__builtin_amdgcn_fdot2)
  return __builtin_amdgcn_fdot2(a, b, c, false);
#else
  return c + (float)a.x * (float)b.x + (float)a.y * (float)b.y;
#endif
}

__device__ __forceinline__ float fastrcp(float x) {
#if __has_builtin(__builtin_amdgcn_rcpf)
  return __builtin_amdgcn_rcpf(x);
#else
  return 1.0f / x;
#endif
}

// LDS-only barrier: do NOT drain vmcnt (global ys stores / gi prefetch
// loads keep flowing across steps). LDS h-exchange is covered by lgkmcnt.
#define BARL() asm volatile("s_waitcnt lgkmcnt(0)\n\ts_barrier" ::: "memory")

// ---------------- phase 1: gi[(t*B+b)*384] (f16) = seq @ Wi ----------------
__global__ __launch_bounds__(256, 2)
void gi_gemm(const float* __restrict__ seq, const float* __restrict__ Wi,
             _Float16* __restrict__ gi) {
  const int tid = threadIdx.x;
  const int w = tid >> 6, lane = tid & 63;
  const int q = lane >> 4, s = lane & 15;

  f16x8 wF[6][4];
#pragma unroll
  for (int j = 0; j < 6; j++) {
    const int col = w * 96 + j * 16 + s;
#pragma unroll
    for (int kk = 0; kk < 4; kk++) {
      f16x8 f;
#pragma unroll
      for (int e = 0; e < 8; e++)
        f[e] = (_Float16)Wi[(size_t)(kk * 32 + q * 8 + e) * 384 + col];
      wF[j][kk] = f;
    }
  }

  __shared__ __align__(16) _Float16 gis[16 * 384];
  const int NROWTILES = (T_STEPS * B_SZ) / 16;

  for (int r = blockIdx.x; r < NROWTILES; r += gridDim.x) {
    const float* xr = &seq[((size_t)r * 16 + s) * D_SZ];
    f16x8 af[4];
#pragma unroll
    for (int kk = 0; kk < 4; kk++) {
      float4 u0 = *(const float4*)(xr + kk * 32 + q * 8);
      float4 u1 = *(const float4*)(xr + kk * 32 + q * 8 + 4);
      f16x8 f;
      f[0] = (_Float16)u0.x; f[1] = (_Float16)u0.y;
      f[2] = (_Float16)u0.z; f[3] = (_Float16)u0.w;
      f[4] = (_Float16)u1.x; f[5] = (_Float16)u1.y;
      f[6] = (_Float16)u1.z; f[7] = (_Float16)u1.w;
      af[kk] = f;
    }
    f32x4 acc[6];
#pragma unroll
    for (int j = 0; j < 6; j++) acc[j] = (f32x4){0.f, 0.f, 0.f, 0.f};
#pragma unroll
    for (int kk = 0; kk < 4; kk++)
#pragma unroll
      for (int j = 0; j < 6; j++)
        acc[j] = __builtin_amdgcn_mfma_f32_16x16x32_f16(af[kk], wF[j][kk],
                                                        acc[j], 0, 0, 0);
#pragma unroll
    for (int j = 0; j < 6; j++) {
      const int col = w * 96 + j * 16 + s;
#pragma unroll
      for (int e = 0; e < 4; e++)
        gis[(q * 4 + e) * 384 + col] = (_Float16)acc[j][e];
    }
    __syncthreads();
    const size_t base = (size_t)r * 16 * 384;
#pragma unroll
    for (int i = 0; i < 3; i++) {
      const int idx = tid + i * 256;
      *(float4*)(gi + base + (size_t)idx * 8) = *(const float4*)(gis + idx * 8);
    }
    __syncthreads();
  }
}

// ---------------- phase 2: latency scan, 4 waves, 2-way k-split -----------
#define GILOAD3(T_, R_, Z_, N_) { \
    int tl_ = (T_); if (tl_ > T_STEPS - 1) tl_ = T_STEPS - 1; \
    const _Float16* gp_ = gi + ((size_t)tl_ * B_SZ + b) * 384; \
    R_ = gp_[c]; Z_ = gp_[128 + c]; N_ = gp_[256 + c]; }

#define STEP3(T_, R_, Z_, N_, Y_) { \
    const int p_ = (T_) & 1; \
    const h2* hb_ = (const h2*)&hh16[p_][g * 64]; \
    float cr0_ = 0.f, cr1_ = 0.f, cz0_ = 0.f, cz1_ = 0.f; \
    float cn0_ = 0.f, cn1_ = 0.f; \
    _Pragma("unroll") for (int j_ = 0; j_ < 16; j_++) { \
      const h2 a_ = hb_[2 * j_], b2_ = hb_[2 * j_ + 1]; \
      cr0_ = dot2f(a_,  whR[0][2 * j_],     cr0_); \
      cr1_ = dot2f(b2_, whR[0][2 * j_ + 1], cr1_); \
      cz0_ = dot2f(a_,  whR[1][2 * j_],     cz0_); \
      cz1_ = dot2f(b2_, whR[1][2 * j_ + 1], cz1_); \
      cn0_ = dot2f(a_,  whR[2][2 * j_],     cn0_); \
      cn1_ = dot2f(b2_, whR[2][2 * j_ + 1], cn1_); \
    } \
    float cr_ = cr0_ + cr1_, cz_ = cz0_ + cz1_, cn_ = cn0_ + cn1_; \
    const float gr_ = (float)R_, gz_ = (float)Z_, gn_ = (float)N_; \
    GILOAD3((T_) + 4, R_, Z_, N_) \
    cr_ += __shfl_xor(cr_, 32, 64); \
    cz_ += __shfl_xor(cz_, 32, 64); \
    cn_ += __shfl_xor(cn_, 32, 64); \
    const float ar_ = cr_ + gr_ + bhr; \
    const float az_ = cz_ + gz_ + bhz; \
    const float ah_ = cn_ + bhn; \
    const float r_ = fastrcp(1.f + __expf(-ar_)); \
    const float z_ = fastrcp(1.f + __expf(-az_)); \
    const float ta_ = gn_ + r_ * ah_; \
    const float e2_ = __expf(2.f * ta_); \
    const float n_ = 1.f - 2.f * fastrcp(e2_ + 1.f);  /* NaN-free tanh */ \
    const float hnew_ = n_ + z_ * (hu - n_); \
    hu = rst[((T_) + 1) & (T_STEPS - 1)] ? h0c : hnew_; \
    if (g0) hh16[p_ ^ 1][c] = (_Float16)hu; \
    Y_ = hnew_; \
    BARL(); }

__global__ __launch_bounds__(256, 1)
void gru_scan3(const _Float16* __restrict__ gi,
               const int* __restrict__ resets,
               const float* __restrict__ h0,
               const float* __restrict__ Wh,
               const float* __restrict__ bh,
               float* __restrict__ out) {
  const int b = blockIdx.x;
  const int tid = threadIdx.x;
  const int w = tid >> 6;                 // wave 0..3
  const int lane = tid & 63;
  const int c = (w << 5) | (lane & 31);   // hidden column 0..127
  const int g = lane >> 5;                // k-half 0/1
  const bool g0 = (g == 0);

  __shared__ int rst[T_STEPS];
  __shared__ __align__(16) _Float16 hh16[2][H_SZ];

  for (int i = tid; i < T_STEPS; i += 256)
    rst[i] = resets[(size_t)i * B_SZ + b];

  // Wh columns {c, 128+c, 256+c}, k in [64g, 64g+64) as 32 h2 each
  h2 whR[3][32];
  const int k0 = g * 64;
#pragma unroll
  for (int ch = 0; ch < 3; ch++) {
    const int col = ch * H_SZ + c;
#pragma unroll
    for (int j = 0; j < 32; j++) {
      const int k = k0 + 2 * j;
      h2 wb; wb.x = (_Float16)Wh[(size_t)k * 384 + col];
             wb.y = (_Float16)Wh[(size_t)(k + 1) * 384 + col];
      whR[ch][j] = wb;
    }
  }

  const float bhr = bh[c], bhz = bh[H_SZ + c], bhn = bh[2 * H_SZ + c];
  const float h0c = h0[(size_t)b * H_SZ + c];
  float hu = h0c;

  if (tid < H_SZ) hh16[0][tid] = (_Float16)h0[(size_t)b * H_SZ + tid];

  _Float16 rA, zA, nA, rB, zB, nB, rC, zC, nC, rD, zD, nD;
  GILOAD3(0, rA, zA, nA)
  GILOAD3(1, rB, zB, nB)
  GILOAD3(2, rC, zC, nC)
  GILOAD3(3, rD, zD, nD)
  __syncthreads();

  float* ys = out + (size_t)B_SZ * H_SZ;  // out = [final_carry] ++ [ys]
  float yb0, yb1, yb2, yb3, yb4, yb5, yb6, yb7;

#pragma unroll 1
  for (int t = 0; t < T_STEPS; t += 8) {
    STEP3(t + 0, rA, zA, nA, yb0)
    STEP3(t + 1, rB, zB, nB, yb1)
    STEP3(t + 2, rC, zC, nC, yb2)
    STEP3(t + 3, rD, zD, nD, yb3)
    STEP3(t + 4, rA, zA, nA, yb4)
    STEP3(t + 5, rB, zB, nB, yb5)
    STEP3(t + 6, rC, zC, nC, yb6)
    STEP3(t + 7, rD, zD, nD, yb7)
    if (!g0) {
      float* yp = &ys[((size_t)t * B_SZ + b) * H_SZ + c];
      const size_t st = (size_t)B_SZ * H_SZ;
      yp[0]      = yb0; yp[st]     = yb1; yp[2 * st] = yb2; yp[3 * st] = yb3;
      yp[4 * st] = yb4; yp[5 * st] = yb5; yp[6 * st] = yb6; yp[7 * st] = yb7;
    }
  }
  if (!g0) out[(size_t)b * H_SZ + c] = yb7;  // final carry = hnew at t=1023
}

// ---------------- fallback: round-2 fused kernel (ws too small) -----------
__global__ __launch_bounds__(512, 2)
void gru_scan_fb(const float* __restrict__ seq,
                 const int* __restrict__ resets,
                 const float* __restrict__ h0,
                 const float* __restrict__ Wi,
                 const float* __restrict__ Wh,
                 const float* __restrict__ bh,
                 float* __restrict__ out) {
  const int b = blockIdx.x;
  const int tid = threadIdx.x;
  const int w = tid >> 6;
  const int lane = tid & 63;
  const int c = (w << 4) | (lane & 15);
  const int g = lane >> 4;

  __shared__ int rst[T_STEPS];
  __shared__ __align__(16) _Float16 x16[2][D_SZ];
  __shared__ __align__(16) _Float16 hh16[2][H_SZ];

  for (int i = tid; i < T_STEPS; i += 512) rst[i] = resets[(size_t)i * B_SZ + b];

  h2 wiR[3][16], whR[3][16];
  const int k0 = g * 32;
#pragma unroll
  for (int ch = 0; ch < 3; ch++) {
    const int col = ch * H_SZ + c;
#pragma unroll
    for (int j = 0; j < 16; j++) {
      const int k = k0 + 2 * j;
      h2 wa; wa.x = (_Float16)Wi[(size_t)k * 384 + col];
             wa.y = (_Float16)Wi[(size_t)(k + 1) * 384 + col];
      wiR[ch][j] = wa;
      h2 wb; wb.x = (_Float16)Wh[(size_t)k * 384 + col];
             wb.y = (_Float16)Wh[(size_t)(k + 1) * 384 + col];
      whR[ch][j] = wb;
    }
  }

  const float bhr = bh[c], bhz = bh[H_SZ + c], bhn = bh[2 * H_SZ + c];
  const float h0c = h0[(size_t)b * H_SZ + c];
  float hu = h0c;

  if (tid < H_SZ) {
    hh16[0][tid] = (_Float16)h0[(size_t)b * H_SZ + tid];
    x16[0][tid]  = (_Float16)seq[((size_t)0 * B_SZ + b) * D_SZ + tid];
  }
  float xA = 0.f, xB = 0.f;
  if (tid < D_SZ) {
    xA = seq[((size_t)1 * B_SZ + b) * D_SZ + tid];
    xB = seq[((size_t)2 * B_SZ + b) * D_SZ + tid];
  }
  __syncthreads();

  float* ys = out + (size_t)B_SZ * H_SZ;

#pragma unroll 1
  for (int t = 0; t < T_STEPS; t++) {
    const int p = t & 1;
    const int rnext = rst[(t + 1) & (T_STEPS - 1)];

    const h8* xb = (const h8*)&x16[p][g * 32];
    const h8* hb = (const h8*)&hh16[p][g * 32];
    float cr = 0.f, cz = 0.f, ci = 0.f, chn = 0.f;
#pragma unroll
    for (int q = 0; q < 4; q++) {
      U8 ux, uh; ux.v = xb[q]; uh.v = hb[q];
#pragma unroll
      for (int j = 0; j < 4; j++) {
        const int idx = q * 4 + j;
        cr  = dot2f(ux.p[j], wiR[0][idx], cr);
        cz  = dot2f(ux.p[j], wiR[1][idx], cz);
        ci  = dot2f(ux.p[j], wiR[2][idx], ci);
        cr  = dot2f(uh.p[j], whR[0][idx], cr);
        cz  = dot2f(uh.p[j], whR[1][idx], cz);
        chn = dot2f(uh.p[j], whR[2][idx], chn);
      }
    }
    cr  += __shfl_xor(cr, 16, 64);
    cz  += __shfl_xor(cz, 16, 64);
    ci  += __shfl_xor(ci, 16, 64);
    chn += __shfl_xor(chn, 16, 64);
    cr  += __shfl_xor(cr, 32, 64);
    cz  += __shfl_xor(cz, 32, 64);
    ci  += __shfl_xor(ci, 32, 64);
    chn += __shfl_xor(chn, 32, 64);

    const float ar = cr + bhr;
    const float az = cz + bhz;
    const float ah = chn + bhn;
    const float r = fastrcp(1.f + __expf(-ar));
    const float z = fastrcp(1.f + __expf(-az));
    const float ta = ci + r * ah;
    const float e2 = __expf(2.f * ta);
    const float n = 1.f - 2.f * fastrcp(e2 + 1.f);
    const float hnew = n + z * (hu - n);
    const float hunew = rnext ? h0c : hnew;
    hu = hunew;

    if (g == 0) {
      ys[((size_t)t * B_SZ + b) * H_SZ + c] = hnew;
      hh16[p ^ 1][c] = (_Float16)hunew;
      if (t == T_STEPS - 1) out[(size_t)b * H_SZ + c] = hnew;
    }
    if (tid < D_SZ) {
      x16[p ^ 1][tid] = (_Float16)xA;
      xA = xB;
      int tt = t + 3; if (tt > T_STEPS - 1) tt = T_STEPS - 1;
      xB = seq[((size_t)tt * B_SZ + b) * D_SZ + tid];
    }
    __syncthreads();
  }
}

extern "C" void kernel_launch(void* const* d_in, const int* in_sizes, int n_in,
                              void* d_out, int out_size, void* d_ws, size_t ws_size,
                              hipStream_t stream) {
  const float* seq    = (const float*)d_in[0];
  const int*   resets = (const int*)d_in[1];
  const float* h0     = (const float*)d_in[2];
  const float* Wi     = (const float*)d_in[3];
  const float* Wh     = (const float*)d_in[4];
  const float* bh     = (const float*)d_in[5];
  (void)in_sizes; (void)n_in; (void)out_size;

  const size_t need = (size_t)T_STEPS * B_SZ * 384 * sizeof(_Float16);
  if (ws_size >= need && d_ws != nullptr) {
    _Float16* gi = (_Float16*)d_ws;
    gi_gemm<<<1024, 256, 0, stream>>>(seq, Wi, gi);
    gru_scan3<<<B_SZ, 256, 0, stream>>>(gi, resets, h0, Wh, bh, (float*)d_out);
  } else {
    gru_scan_fb<<<B_SZ, 512, 0, stream>>>(seq, resets, h0, Wi, Wh, bh,
                                          (float*)d_out);
  }
}